// Round 3
// baseline (705.661 us; speedup 1.0000x reference)
//
#include <hip/hip_runtime.h>

#define T 64
#define B 64
#define V 32000
#define E 32
#define H 8
// pre-row stride (padded 10 -> 12 floats for float4 alignment)
#define PSTR 12

typedef float f32x4 __attribute__((ext_vector_type(4)));

__device__ __forceinline__ float fast_rcp(float x) { return __builtin_amdgcn_rcpf(x); }
__device__ __forceinline__ float sigmoid_f(float x) { return fast_rcp(1.0f + __expf(-x)); }
__device__ __forceinline__ float tanh_f(float x) { return 1.0f - 2.0f * fast_rcp(__expf(2.0f * x) + 1.0f); }

// ---------------------------------------------------------------------------
// K1: embedding gather + e-projections for both directions.
// pre[dir][(i*B+b)*PSTR + {0:az, 1:ar, 2..9:ah[8]}], i = scan-step index.
// dir0 processes enc[i]; dir1 processes enc[T-1-i] (reversed scan input).
// ---------------------------------------------------------------------------
__global__ void __launch_bounds__(64) precompute_kernel(
    const int* __restrict__ x, const float* __restrict__ emb,
    const float* __restrict__ Wz1, const float* __restrict__ bz1,
    const float* __restrict__ Wr1, const float* __restrict__ br1,
    const float* __restrict__ Wh1, const float* __restrict__ bh1,
    const float* __restrict__ Wz2, const float* __restrict__ bz2,
    const float* __restrict__ Wr2, const float* __restrict__ br2,
    const float* __restrict__ Wh2, const float* __restrict__ bh2,
    float* __restrict__ pre)
{
    const int i = blockIdx.x;     // scan step
    const int dir = blockIdx.y;   // 0 fwd, 1 bwd
    const int b = threadIdx.x;    // batch row

    const float* Wz = dir ? Wz2 : Wz1;  const float* bz = dir ? bz2 : bz1;
    const float* Wr = dir ? Wr2 : Wr1;  const float* br = dir ? br2 : br1;
    const float* Wh = dir ? Wh2 : Wh1;  const float* bh = dir ? bh2 : bh1;

    const int pos = dir ? (T - 1 - i) : i;
    const int idx = x[pos * B + b];

    float e[E];
    const float4* e4p = reinterpret_cast<const float4*>(emb + (size_t)idx * E);
#pragma unroll
    for (int q = 0; q < E / 4; q++) {
        float4 t = e4p[q];
        e[q*4+0] = t.x; e[q*4+1] = t.y; e[q*4+2] = t.z; e[q*4+3] = t.w;
    }

    float az = bz[0], ar = br[0];
    float ah[H];
#pragma unroll
    for (int j = 0; j < H; j++) ah[j] = bh[j];

#pragma unroll
    for (int d = 0; d < E; d++) {
        const float ed = e[d];
        az += ed * Wz[H + d];
        ar += ed * Wr[H + d];
#pragma unroll
        for (int j = 0; j < H; j++) ah[j] += ed * Wh[(H + d) * H + j];
    }

    float* dst = pre + ((size_t)dir * T * B + i * B + b) * PSTR;
    float4 s0 = {az, ar, ah[0], ah[1]};
    float4 s1 = {ah[2], ah[3], ah[4], ah[5]};
    float4 s2 = {ah[6], ah[7], 0.0f, 0.0f};
    *reinterpret_cast<float4*>(dst + 0) = s0;
    *reinterpret_cast<float4*>(dst + 4) = s1;
    *reinterpret_cast<float4*>(dst + 8) = s2;
}

// ---------------------------------------------------------------------------
// K2: the sequential recurrence. 2 blocks (fwd/bwd) x 64 lanes (batch rows).
// Emits the PRE-update hidden state at each step into th[(t*B+b)*16 + dir*8].
// ---------------------------------------------------------------------------
__global__ void __launch_bounds__(64) gru_scan_kernel(
    const float* __restrict__ Wz1, const float* __restrict__ Wr1, const float* __restrict__ Wh1,
    const float* __restrict__ Wz2, const float* __restrict__ Wr2, const float* __restrict__ Wh2,
    const float* __restrict__ pre, float* __restrict__ th)
{
    const int dir = blockIdx.x;
    const int b = threadIdx.x;
    const float* Wz = dir ? Wz2 : Wz1;
    const float* Wr = dir ? Wr2 : Wr1;
    const float* Wh = dir ? Wh2 : Wh1;

    // h-recurrence weights into registers (block-uniform loads)
    float wzh[H], wrh[H], whh[H * H];
#pragma unroll
    for (int k = 0; k < H; k++) { wzh[k] = Wz[k]; wrh[k] = Wr[k]; }
#pragma unroll
    for (int d = 0; d < H; d++)
#pragma unroll
        for (int j = 0; j < H; j++) whh[d * H + j] = Wh[d * H + j];

    float h[H];
#pragma unroll
    for (int j = 0; j < H; j++) h[j] = 0.0f;

    const float* preD = pre + (size_t)dir * T * B * PSTR;
    // prefetch step 0
    const float4* p4 = reinterpret_cast<const float4*>(preD + (size_t)b * PSTR);
    float4 p0 = p4[0], p1 = p4[1], p2 = p4[2];

    for (int i = 0; i < T; i++) {
        const int pos = dir ? (T - 1 - i) : i;

        // store PRE-update state
        float* dst = th + ((size_t)pos * B + b) * 16 + dir * 8;
        float4 s0 = {h[0], h[1], h[2], h[3]};
        float4 s1 = {h[4], h[5], h[6], h[7]};
        *reinterpret_cast<float4*>(dst + 0) = s0;
        *reinterpret_cast<float4*>(dst + 4) = s1;

        const float az = p0.x, ar = p0.y;
        float ah[H] = {p0.z, p0.w, p1.x, p1.y, p1.z, p1.w, p2.x, p2.y};

        // prefetch next step while computing this one
        const int ni = (i < T - 1) ? (i + 1) : (T - 1);
        const float4* n4 = reinterpret_cast<const float4*>(preD + ((size_t)ni * B + b) * PSTR);
        p0 = n4[0]; p1 = n4[1]; p2 = n4[2];

        float zx = az, rx = ar;
#pragma unroll
        for (int k = 0; k < H; k++) { zx += h[k] * wzh[k]; rx += h[k] * wrh[k]; }
        const float z = sigmoid_f(zx);
        const float r = sigmoid_f(rx);

        float hc[H];
#pragma unroll
        for (int j = 0; j < H; j++) hc[j] = ah[j];
#pragma unroll
        for (int d = 0; d < H; d++) {
            const float rh = r * h[d];
#pragma unroll
            for (int j = 0; j < H; j++) hc[j] += rh * whh[d * H + j];
        }
#pragma unroll
        for (int j = 0; j < H; j++) {
            const float c = tanh_f(hc[j]);
            h[j] += z * (c - h[j]);   // (1-z)h + z*c
        }
    }
}

// ---------------------------------------------------------------------------
// K3: logits + log_softmax, software-pipelined over TWO row groups of 8.
// 256 blocks x 512 threads; block owns R=16 rows. 3 phases:
//   P1: sumexp(rows 0-7)                      (compute only, ~13 us)
//   P2: sumexp(rows 8-15) + store(rows 0-7)   (compute hides under stores)
//   P3: store(rows 8-15)                      (store-bound)
// Phase count kept at 3 (not 5): each phase re-streams the full 2 MB Wout,
// so L2 read traffic = phases x 256 x 2 MB. 3 phases = 1.5 GB (~14 TB/s
// demand) vs 5 phases = 2.6 GB (~24 TB/s, contending with the store stream).
// No max-subtraction needed: |h|<=1, |Wout|,|bout|<=0.25 -> |logit|<=4.25,
// sum(exp) <= 2.3e6, well inside fp32.
// Non-temporal stores keep the 512 MB output stream from evicting the 2 MB
// Wout tile out of each XCD's L2.
// hlds reads are wave-uniform -> LDS broadcast path (conflict-free).
// ---------------------------------------------------------------------------
#define R 16
#define RS 8
#define NG (R / RS)
#define V4 (V / 4)          // 8000 float4 columns
#define K3_THREADS 512
#define K3_WAVES (K3_THREADS / 64)

__device__ __forceinline__ float4 dot16(const float4 bb, const float4* w, const float* hrow) {
    float ax = bb.x, ay = bb.y, az = bb.z, aw = bb.w;
#pragma unroll
    for (int k4 = 0; k4 < 4; k4++) {
        const float4 hh = *reinterpret_cast<const float4*>(hrow + k4 * 4);
        ax += hh.x * w[k4*4+0].x; ay += hh.x * w[k4*4+0].y; az += hh.x * w[k4*4+0].z; aw += hh.x * w[k4*4+0].w;
        ax += hh.y * w[k4*4+1].x; ay += hh.y * w[k4*4+1].y; az += hh.y * w[k4*4+1].z; aw += hh.y * w[k4*4+1].w;
        ax += hh.z * w[k4*4+2].x; ay += hh.z * w[k4*4+2].y; az += hh.z * w[k4*4+2].z; aw += hh.z * w[k4*4+2].w;
        ax += hh.w * w[k4*4+3].x; ay += hh.w * w[k4*4+3].y; az += hh.w * w[k4*4+3].z; aw += hh.w * w[k4*4+3].w;
    }
    return {ax, ay, az, aw};
}

// One pipeline phase: sum-of-exp rows [SE0, SE0+SEN) and store rows
// [ST0, ST0+STN). All row indices compile-time -> l[]/lse[] stay in VGPRs.
template<int SE0, int SEN, int ST0, int STN>
__device__ __forceinline__ void k3_phase(
    const float4* __restrict__ W4, const float4* __restrict__ b4p,
    float* __restrict__ out, const float (&hlds)[R][16],
    float (&l)[R], const float (&lse)[R], int tid, int row0)
{
    for (int v4 = tid; v4 < V4; v4 += K3_THREADS) {
        asm volatile("" ::: "memory");   // re-read hlds from LDS each iter (keeps VGPRs low)
        float4 w[16];
#pragma unroll
        for (int k = 0; k < 16; k++) w[k] = W4[(size_t)k * V4 + v4];
        const float4 bb = b4p[v4];

#pragma unroll
        for (int r = 0; r < STN; r++) {
            const int rr = ST0 + r;
            const float4 o = dot16(bb, w, &hlds[rr][0]);
            f32x4 res = {o.x - lse[rr], o.y - lse[rr], o.z - lse[rr], o.w - lse[rr]};
            f32x4* dst = reinterpret_cast<f32x4*>(out + ((size_t)(row0 + rr) * V4 + v4) * 4);
            __builtin_nontemporal_store(res, dst);
        }
#pragma unroll
        for (int r = 0; r < SEN; r++) {
            const int rr = SE0 + r;
            const float4 o = dot16(bb, w, &hlds[rr][0]);
            l[rr] += (__expf(o.x) + __expf(o.y)) + (__expf(o.z) + __expf(o.w));
        }
    }
}

// Block-wide reduction of group G0/RS's sum-of-exp; writes lse[G0..G0+RS).
template<int G0>
__device__ __forceinline__ void k3_reduce(
    float (&l)[R], float (&lse)[R],
    float (*red)[K3_WAVES][RS], int tid)
{
    float v[RS];
#pragma unroll
    for (int r = 0; r < RS; r++) {
        v[r] = l[G0 + r];
#pragma unroll
        for (int m = 1; m < 64; m <<= 1) v[r] += __shfl_xor(v[r], m, 64);
    }
    const int lane = tid & 63, wid = tid >> 6;
    if (lane == 0) {
#pragma unroll
        for (int r = 0; r < RS; r++) red[G0 / RS][wid][r] = v[r];
    }
    __syncthreads();
#pragma unroll
    for (int r = 0; r < RS; r++) {
        float t = 0.0f;
#pragma unroll
        for (int w = 0; w < K3_WAVES; w++) t += red[G0 / RS][w][r];
        lse[G0 + r] = logf(t);
    }
}

__global__ void __launch_bounds__(K3_THREADS) logits_kernel(
    const float* __restrict__ th, const float* __restrict__ Wout,
    const float* __restrict__ bout, float* __restrict__ out)
{
    __shared__ __align__(16) float hlds[R][16];
    __shared__ float red[NG][K3_WAVES][RS];

    const int tid = threadIdx.x;
    const int row0 = blockIdx.x * R;

    if (tid < R * 4) {  // 16 rows x 4 float4 = 64 float4
        reinterpret_cast<float4*>(hlds)[tid] =
            reinterpret_cast<const float4*>(th + (size_t)row0 * 16)[tid];
    }
    __syncthreads();

    const float4* W4 = reinterpret_cast<const float4*>(Wout);
    const float4* b4p = reinterpret_cast<const float4*>(bout);

    float l[R], lse[R];
#pragma unroll
    for (int r = 0; r < R; r++) { l[r] = 0.0f; lse[r] = 0.0f; }

    // P1: sumexp(0-7); P2: sumexp(8-15) + store(0-7); P3: store(8-15)
    k3_phase<0,  RS, 0, 0 >(W4, b4p, out, hlds, l, lse, tid, row0);
    k3_reduce<0>(l, lse, red, tid);
    k3_phase<RS, RS, 0, RS>(W4, b4p, out, hlds, l, lse, tid, row0);
    k3_reduce<RS>(l, lse, red, tid);
    k3_phase<0, 0, RS, RS>(W4, b4p, out, hlds, l, lse, tid, row0);
}

// ---------------------------------------------------------------------------
extern "C" void kernel_launch(void* const* d_in, const int* in_sizes, int n_in,
                              void* d_out, int out_size, void* d_ws, size_t ws_size,
                              hipStream_t stream) {
    const int*   x    = (const int*)  d_in[0];
    const float* emb  = (const float*)d_in[1];
    const float* Wz1  = (const float*)d_in[2];  const float* bz1 = (const float*)d_in[3];
    const float* Wr1  = (const float*)d_in[4];  const float* br1 = (const float*)d_in[5];
    const float* Wh1  = (const float*)d_in[6];  const float* bh1 = (const float*)d_in[7];
    const float* Wz2  = (const float*)d_in[8];  const float* bz2 = (const float*)d_in[9];
    const float* Wr2  = (const float*)d_in[10]; const float* br2 = (const float*)d_in[11];
    const float* Wh2  = (const float*)d_in[12]; const float* bh2 = (const float*)d_in[13];
    const float* Wout = (const float*)d_in[14]; const float* bout = (const float*)d_in[15];
    float* out = (float*)d_out;

    float* ws = (float*)d_ws;
    float* th  = ws;                       // T*B*16 = 65536 floats
    float* pre = ws + (size_t)T * B * 16;  // 2 * T*B*PSTR = 98304 floats

    precompute_kernel<<<dim3(T, 2), B, 0, stream>>>(
        x, emb, Wz1, bz1, Wr1, br1, Wh1, bh1, Wz2, bz2, Wr2, br2, Wh2, bh2, pre);
    gru_scan_kernel<<<2, B, 0, stream>>>(Wz1, Wr1, Wh1, Wz2, Wr2, Wh2, pre, th);
    logits_kernel<<<256, K3_THREADS, 0, stream>>>(th, Wout, bout, out);
}